// Round 8
// baseline (498.019 us; speedup 1.0000x reference)
//
#include <hip/hip_runtime.h>
#include <float.h>

// Sparsemax per row; one 256-thread block per row; input read exactly once.
// Lesson R1/R5/R6: never keep 32 row-floats/thread live -> chunked scan with
// <=8 live row registers. Row parked in LDS as f16 (|err|<=0.002 << 2e-2).
// Candidates (superset of support) gathered per-chunk against a FIXED
// threshold thr0 = (wave max of chunk 0) - 1 <= block_max - 1 <= tau, so no
// re-scan is ever needed; Newton's (> tau) filter drops the junk. ONE barrier.

constexpr int D       = 8192;
constexpr int THREADS = 256;
constexpr int CHUNKS  = D / (THREADS * 4);   // 8 chunks of 1024 elements
constexpr int WCAP    = 128;                 // per-wave candidate capacity

typedef float    f32x4 __attribute__((ext_vector_type(4)));
typedef _Float16 f16x4 __attribute__((ext_vector_type(4)));

__global__ __launch_bounds__(THREADS, 8)     // 8 blocks/CU (LDS 18.5K, VGPR<=64)
void sparsemax_kernel(const float* __restrict__ x, float* __restrict__ out,
                      int rows) {
    __shared__ f16x4 hrow4[D / 4];           // 16 KiB f16 row copy
    __shared__ float cands[4][WCAP];         // 2 KiB candidate lists
    __shared__ float redm[4];
    __shared__ int   ncnt[4];

    const int tid  = threadIdx.x;
    const int wave = tid >> 6, lane = tid & 63;
    const long long row = blockIdx.x;
    if (row >= rows) return;
    const f32x4* __restrict__ xr4 = reinterpret_cast<const f32x4*>(x + row * D);
    f32x4* __restrict__       or4 = reinterpret_cast<f32x4*>(out + row * D);
    const unsigned long long lmask = (1ull << lane) - 1ull;

    // ---- chunk 0: load, stash, wave max -> fixed gather threshold ----
    f32x4 cur = xr4[tid];
    f32x4 nxt = xr4[tid + THREADS];          // prefetch chunk 1
    hrow4[tid] = __builtin_convertvector(cur, f16x4);
    float m = fmaxf(fmaxf(cur.x, cur.y), fmaxf(cur.z, cur.w));
    float cm = m;
    #pragma unroll
    for (int off = 1; off < 64; off <<= 1)
        cm = fmaxf(cm, __shfl_xor(cm, off, 64));
    const float thr = cm - 1.0f;             // <= block_max - 1 <= tau

    // gather chunk 0 from live registers
    int n = 0;
    #pragma unroll
    for (int j = 0; j < 4; ++j) {
        float v = cur[j];
        unsigned long long mk = __ballot(v > thr);
        if (v > thr) {
            int pos = n + __popcll(mk & lmask);
            if (pos < WCAP) cands[wave][pos] = v;
        }
        n += __popcll(mk);
    }

    // ---- chunks 1..7: double-buffered; stash + per-lane max + gather ----
    #pragma unroll
    for (int c = 1; c < CHUNKS; ++c) {
        cur = nxt;
        if (c + 1 < CHUNKS) nxt = xr4[tid + (c + 1) * THREADS];
        hrow4[tid + c * THREADS] = __builtin_convertvector(cur, f16x4);
        m = fmaxf(m, fmaxf(fmaxf(cur.x, cur.y), fmaxf(cur.z, cur.w)));
        #pragma unroll
        for (int j = 0; j < 4; ++j) {
            float v = cur[j];
            unsigned long long mk = __ballot(v > thr);
            if (v > thr) {
                int pos = n + __popcll(mk & lmask);
                if (pos < WCAP) cands[wave][pos] = v;
            }
            n += __popcll(mk);
        }
    }

    // ---- wave max (once) -> LDS; ONE barrier ----
    #pragma unroll
    for (int off = 1; off < 64; off <<= 1)
        m = fmaxf(m, __shfl_xor(m, off, 64));
    if (lane == 0) { redm[wave] = m; ncnt[wave] = n; }
    __syncthreads();

    // ---- block max; per-wave independent shuffle-only Newton/Michelot ----
    const float bm = fmaxf(fmaxf(redm[0], redm[1]), fmaxf(redm[2], redm[3]));
    const int n0 = ncnt[0], n1 = ncnt[1], n2 = ncnt[2], n3 = ncnt[3];
    float tau = bm - 1.0f;                   // f(tau0) >= 0 -> ascend to exact
    float kprev = -1.0f;

    if (n0 <= WCAP && n1 <= WCAP && n2 <= WCAP && n3 <= WCAP) {
        const float c0 = (lane      < n0) ? cands[0][lane     ] : -FLT_MAX;
        const float c1 = (lane + 64 < n0) ? cands[0][lane + 64] : -FLT_MAX;
        const float c2 = (lane      < n1) ? cands[1][lane     ] : -FLT_MAX;
        const float c3 = (lane + 64 < n1) ? cands[1][lane + 64] : -FLT_MAX;
        const float c4 = (lane      < n2) ? cands[2][lane     ] : -FLT_MAX;
        const float c5 = (lane + 64 < n2) ? cands[2][lane + 64] : -FLT_MAX;
        const float c6 = (lane      < n3) ? cands[3][lane     ] : -FLT_MAX;
        const float c7 = (lane + 64 < n3) ? cands[3][lane + 64] : -FLT_MAX;
        for (int it = 0; it < 64; ++it) {    // wave-uniform trip count
            float S = 0.f, K = 0.f;
            if (c0 > tau) { S += c0; K += 1.f; }
            if (c1 > tau) { S += c1; K += 1.f; }
            if (c2 > tau) { S += c2; K += 1.f; }
            if (c3 > tau) { S += c3; K += 1.f; }
            if (c4 > tau) { S += c4; K += 1.f; }
            if (c5 > tau) { S += c5; K += 1.f; }
            if (c6 > tau) { S += c6; K += 1.f; }
            if (c7 > tau) { S += c7; K += 1.f; }
            #pragma unroll
            for (int off = 1; off < 64; off <<= 1) {
                S += __shfl_xor(S, off, 64);
                K += __shfl_xor(K, off, 64);
            }
            tau = (S - 1.f) / K;             // K >= 1: block max is in support
            if (K == kprev) break;           // support fixed -> exact tau
            kprev = K;
        }
    } else {
        // Fallback (P~0 for Gaussian): full-row Michelot over the f16 copy.
        for (int it = 0; it < 64; ++it) {
            float S = 0.f, K = 0.f;
            for (int i = 0; i < 32; ++i) {
                f16x4 hv = hrow4[lane + i * 64];
                #pragma unroll
                for (int j = 0; j < 4; ++j) {
                    float v = (float)hv[j];
                    if (v > tau) { S += v; K += 1.f; }
                }
            }
            #pragma unroll
            for (int off = 1; off < 64; off <<= 1) {
                S += __shfl_xor(S, off, 64);
                K += __shfl_xor(K, off, 64);
            }
            tau = (S - 1.f) / K;
            if (K == kprev) break;
            kprev = K;
        }
    }

    // ---- output from own f16 LDS slots; nontemporal f32x4 stores ----
    #pragma unroll
    for (int i = 0; i < CHUNKS; ++i) {
        f16x4 hv = hrow4[tid + i * THREADS];
        f32x4 o;
        o.x = fmaxf((float)hv.x - tau, 0.f);
        o.y = fmaxf((float)hv.y - tau, 0.f);
        o.z = fmaxf((float)hv.z - tau, 0.f);
        o.w = fmaxf((float)hv.w - tau, 0.f);
        __builtin_nontemporal_store(o, &or4[tid + i * THREADS]);
    }
}

extern "C" void kernel_launch(void* const* d_in, const int* in_sizes, int n_in,
                              void* d_out, int out_size, void* d_ws, size_t ws_size,
                              hipStream_t stream) {
    const float* x = (const float*)d_in[0];
    float* out = (float*)d_out;
    const int rows = in_sizes[0] / D;            // 4096
    sparsemax_kernel<<<rows, THREADS, 0, stream>>>(x, out, rows);
}

// Round 9
// 298.221 us; speedup vs baseline: 1.6700x; 1.6700x over previous
//
#include <hip/hip_runtime.h>
#include <float.h>

// Sparsemax per row. R3 structure (LDS row staging) repaired:
//  - f16 LDS row: 16 KB -> 8 blocks/CU (R3: 37 KB f32 -> 4 blocks, 32% occ)
//  - ONE barrier (R3 had ~17): after it each wave redundantly scans the LDS
//    row, gathers candidates > block_max-1 (superset of support; tau >= max-1
//    bound), runs shuffle-only Newton on its own list. Identical data -> all
//    waves converge to identical tau.
//  - Register pressure minimal in all phases (R1/R5/R6/R8 lesson: any design
//    keeping 32 row-floats/thread live remats, spills, or serializes).

constexpr int D       = 8192;
constexpr int THREADS = 256;
constexpr int NV      = D / (THREADS * 4);  // 8 f32x4 per thread
constexpr int WCAP    = 128;                // per-wave candidate capacity

typedef float    f32x4 __attribute__((ext_vector_type(4)));
typedef _Float16 f16x4 __attribute__((ext_vector_type(4)));

__global__ __launch_bounds__(THREADS, 8)
void sparsemax_kernel(const float* __restrict__ x, float* __restrict__ out,
                      int rows) {
    __shared__ f16x4 hrow[D / 4];           // 16 KiB f16 row
    __shared__ float wlist[4][WCAP];        // 2 KiB per-wave candidate lists
    __shared__ float redm[4];

    const int tid  = threadIdx.x;
    const int wave = tid >> 6, lane = tid & 63;
    const long long row = blockIdx.x;
    if (row >= rows) return;
    const f32x4* __restrict__ xr4 = reinterpret_cast<const f32x4*>(x + row * D);
    f32x4* __restrict__       or4 = reinterpret_cast<f32x4*>(out + row * D);
    const unsigned long long lmask = (1ull << lane) - 1ull;

    // ---- phase 1: stream row -> f16 LDS, per-thread max (values die here)
    float m = -FLT_MAX;
    for (int i = 0; i < NV; ++i) {
        f32x4 t = xr4[tid + i * THREADS];
        hrow[tid + i * THREADS] = __builtin_convertvector(t, f16x4);
        m = fmaxf(m, fmaxf(fmaxf(t.x, t.y), fmaxf(t.z, t.w)));
    }
    #pragma unroll
    for (int off = 1; off < 64; off <<= 1)
        m = fmaxf(m, __shfl_xor(m, off, 64));
    if (lane == 0) redm[wave] = m;

    __syncthreads();                        // the ONLY barrier

    // ---- phase 2: per-wave full-row LDS scan, ballot-compact candidates
    const float bm  = fmaxf(fmaxf(redm[0], redm[1]), fmaxf(redm[2], redm[3]));
    const float thr = bm - 1.0f;            // tau >= bm-1 always
    int n = 0;
    for (int i = 0; i < 32; ++i) {          // 64 lanes x 32 = 2048 f16x4 slots
        f16x4 hv = hrow[lane + i * 64];
        float v0 = (float)hv.x, v1 = (float)hv.y;
        float v2 = (float)hv.z, v3 = (float)hv.w;
        float mx = fmaxf(fmaxf(v0, v1), fmaxf(v2, v3));
        if (__ballot(mx > thr) == 0ull) continue;   // fast skip (common case)
        #pragma unroll
        for (int j = 0; j < 4; ++j) {
            float v = (j == 0) ? v0 : (j == 1) ? v1 : (j == 2) ? v2 : v3;
            unsigned long long mk = __ballot(v > thr);
            if (v > thr) {
                int pos = n + __popcll(mk & lmask);
                if (pos < WCAP) wlist[wave][pos] = v;
            }
            n += __popcll(mk);
        }
    }

    // ---- Newton/Michelot, shuffle-only, own-wave list (no barrier needed)
    float tau = thr;
    float kprev = -1.0f;
    if (n <= WCAP) {
        const float cA = (lane      < n) ? wlist[wave][lane     ] : -FLT_MAX;
        const float cB = (lane + 64 < n) ? wlist[wave][lane + 64] : -FLT_MAX;
        for (int it = 0; it < 64; ++it) {   // wave-uniform trip count
            float S = 0.f, K = 0.f;
            if (cA > tau) { S += cA; K += 1.f; }
            if (cB > tau) { S += cB; K += 1.f; }
            #pragma unroll
            for (int off = 1; off < 64; off <<= 1) {
                S += __shfl_xor(S, off, 64);
                K += __shfl_xor(K, off, 64);
            }
            tau = (S - 1.f) / K;            // K >= 1: block max in support
            if (K == kprev) break;          // support fixed -> exact tau
            kprev = K;
        }
    } else {
        // Fallback (P~0 for Gaussian): full-row Michelot over the f16 copy.
        for (int it = 0; it < 64; ++it) {
            float S = 0.f, K = 0.f;
            for (int i = 0; i < 32; ++i) {
                f16x4 hv = hrow[lane + i * 64];
                #pragma unroll
                for (int j = 0; j < 4; ++j) {
                    float v = (float)hv[j];
                    if (v > tau) { S += v; K += 1.f; }
                }
            }
            #pragma unroll
            for (int off = 1; off < 64; off <<= 1) {
                S += __shfl_xor(S, off, 64);
                K += __shfl_xor(K, off, 64);
            }
            tau = (S - 1.f) / K;
            if (K == kprev) break;
            kprev = K;
        }
    }

    // ---- phase 3: output from own f16 LDS slots, nontemporal stores
    for (int i = 0; i < NV; ++i) {
        f16x4 hv = hrow[tid + i * THREADS];
        f32x4 o;
        o.x = fmaxf((float)hv.x - tau, 0.f);
        o.y = fmaxf((float)hv.y - tau, 0.f);
        o.z = fmaxf((float)hv.z - tau, 0.f);
        o.w = fmaxf((float)hv.w - tau, 0.f);
        __builtin_nontemporal_store(o, &or4[tid + i * THREADS]);
    }
}

extern "C" void kernel_launch(void* const* d_in, const int* in_sizes, int n_in,
                              void* d_out, int out_size, void* d_ws, size_t ws_size,
                              hipStream_t stream) {
    const float* x = (const float*)d_in[0];
    float* out = (float*)d_out;
    const int rows = in_sizes[0] / D;           // 4096
    sparsemax_kernel<<<rows, THREADS, 0, stream>>>(x, out, rows);
}